// Round 9
// baseline (28.854 us; speedup 1.0000x reference)
//
#include <hip/hip_runtime.h>
#include <hip/hip_fp16.h>

// Problem constants (match reference)
constexpr int B  = 4;
constexpr int C  = 3;
constexpr int F  = 5;
constexpr int HO = 256;
constexpr int WO = 256;
constexpr int HI = HO + F - 1; // 260
constexpr int WI = WO + F - 1; // 260
constexpr int P  = HO * WO;    // 65536 pixels per (b, map)
constexpr int FF = F * F;      // 25
constexpr int PI = HI * WI;    // 67600 input pixels per (b, c)

// Block = 256 threads = 4 waves; covers pixels (y0..y0+3, x0..x0+63).
// Wave w owns y-row y0+w: ALL 25 taps for its 64 pixels -> no inter-wave
// reduce, single barrier after staging, direct coalesced stores.
// Tile: rows [y0-7, y0+13] (21), cols [x0-7, x0+72] (80), fp16-packed uint2.
// Out-of-tile offsets (P ~ 1e-9/sample) -> rare global fallback.
constexpr int TROWS = 21;
constexpr int TCOLS = 80;
constexpr int TSTRIDE = 81;            // 8B units
constexpr int TN = TROWS * TCOLS;      // 1680 entries
constexpr int AMAX = (TROWS - 2) * TSTRIDE + (TCOLS - 2);

__device__ __forceinline__ uint2 pack3(float a, float b, float c) {
    __half2 ab = __floats2half2_rn(a, b);
    __half2 cz = __floats2half2_rn(c, 0.0f);
    uint2 r;
    r.x = *reinterpret_cast<const unsigned int*>(&ab);
    r.y = *reinterpret_cast<const unsigned int*>(&cz);
    return r;
}

__device__ __forceinline__ void fmacc(uint2 v, float w,
                                      float& a0, float& a1, float& a2) {
    __half2 ab = *reinterpret_cast<const __half2*>(&v.x);
    __half2 cz = *reinterpret_cast<const __half2*>(&v.y);
    // (float)half * f32 + f32 acc -> v_fma_mix_f32
    a0 += __half2float(__low2half(ab))  * w;
    a1 += __half2float(__high2half(ab)) * w;
    a2 += __half2float(__low2half(cz))  * w;
}

__global__ __launch_bounds__(256, 4) void dsepconv_kernel(
    const float* __restrict__ inp,   // (B, C, HI, WI)
    const float* __restrict__ vert,  // (B, F, HO, WO)
    const float* __restrict__ horz,  // (B, F, HO, WO)
    const float* __restrict__ offX,  // -> py (vertical), per reference
    const float* __restrict__ offY,  // -> px (horizontal), per reference
    const float* __restrict__ mask,  // (B, F*F, HO, WO)
    float* __restrict__ out)         // (B, C, HO, WO)
{
    __shared__ uint2 tileq[TROWS * TSTRIDE];  // 13,608 B

    const int tid  = threadIdx.x;
    const int lane = tid & 63;
    const int wave = tid >> 6;                 // 0..3 == y-row within patch

    // Grid: bx = b*256 + yblk*4 + xblk ; patch origin (y0, x0)
    const int bx   = blockIdx.x;
    const int x0   = (bx & 3) * 64;
    const int y0   = ((bx >> 2) & 63) * 4;
    const int b    = bx >> 8;

    const float* in0 = inp + (size_t)b * C * PI;
    const float* in1 = in0 + PI;
    const float* in2 = in1 + PI;

    // ---- Stage tile: rows [y0-7, y0+13], cols [x0-7, x0+72] ----
    const int ry0 = y0 - 7;
    const int cx0 = x0 - 7;
#pragma unroll 1
    for (int e = tid; e < TN; e += 256) {
        int trow = e / TCOLS;
        int tcol = e - trow * TCOLS;
        int gy = min(max(ry0 + trow, 0), HI - 1);
        int gx = min(max(cx0 + tcol, 0), WI - 1);
        int g = gy * WI + gx;
        tileq[trow * TSTRIDE + tcol] = pack3(in0[g], in1[g], in2[g]);
    }
    __syncthreads();   // the ONLY barrier; waves independent afterwards

    const int x   = x0 + lane;
    const int y   = y0 + wave;
    const int pix = y * WO + x;

    const float* offXb = offX + (size_t)b * FF * P + pix;
    const float* offYb = offY + (size_t)b * FF * P + pix;
    const float* maskb = mask + (size_t)b * FF * P + pix;
    const float* vb    = vert + (size_t)b * F * P + pix;
    const float* hb    = horz + (size_t)b * F * P + pix;

    float acc0 = 0.f, acc1 = 0.f, acc2 = 0.f;

#pragma unroll 1
    for (int i = 0; i < F; ++i) {
        const float v = vb[i * P];
        const float py_base = (float)(y + i - 1);

#pragma unroll 1
        for (int j = 0; j < F; ++j) {
            const int k = i * F + j;

            float oy = offYb[k * P];
            float ox = offXb[k * P];
            float m  = maskb[k * P];
            float h  = hb[j * P];

            // px = clip(offY + x + j - half + 1, 0, WI-1); half = 2
            float px = fminf(fmaxf(oy + (float)(x + j - 1), 0.0f), (float)(WI - 1));
            float py = fminf(fmaxf(ox + py_base, 0.0f), (float)(HI - 1));

            float lf = floorf(px);
            float tf = floorf(py);
            int l = (int)lf;
            int t = (int)tf;
            float wx = 1.0f - (px - lf);
            float wy = 1.0f - (py - tf);

            // Bilinear identity: clamped edge => r/bottom weights exactly 0,
            // so always read l+1 / t+1 (tile has the +1 margin).
            float w   = v * h * m;
            float wyw = wy * w;
            float wbw = w - wyw;
            float wtl = wx * wyw;
            float wtr = wyw - wtl;
            float wbl = wx * wbw;
            float wbr = wbw - wbl;

            int lt = t - ry0;
            int ll = l - cx0;
            bool ok = ((unsigned)lt <= TROWS - 2) & ((unsigned)ll <= TCOLS - 2);

            int a = min(max(lt * TSTRIDE + ll, 0), AMAX); // safe for !ok lanes

            uint2 g_tl = tileq[a];
            uint2 g_tr = tileq[a + 1];
            uint2 g_bl = tileq[a + TSTRIDE];
            uint2 g_br = tileq[a + TSTRIDE + 1];

            // rare fallback: offset beyond tile margin (~1e-9/sample)
            if (__any(!ok)) {
                if (!ok) {
                    int r  = min(l + 1, WI - 1);
                    int bt = min(t + 1, HI - 1);
                    int o_tl = t * WI + l,  o_tr = t * WI + r;
                    int o_bl = bt * WI + l, o_br = bt * WI + r;
                    g_tl = pack3(in0[o_tl], in1[o_tl], in2[o_tl]);
                    g_tr = pack3(in0[o_tr], in1[o_tr], in2[o_tr]);
                    g_bl = pack3(in0[o_bl], in1[o_bl], in2[o_bl]);
                    g_br = pack3(in0[o_br], in1[o_br], in2[o_br]);
                }
            }

            fmacc(g_tl, wtl, acc0, acc1, acc2);
            fmacc(g_tr, wtr, acc0, acc1, acc2);
            fmacc(g_bl, wbl, acc0, acc1, acc2);
            fmacc(g_br, wbr, acc0, acc1, acc2);
        }
    }

    // Direct coalesced store: wave owns a full y-row segment
    float* ob = out + (size_t)b * C * P + pix;
    ob[0]     = acc0;
    ob[P]     = acc1;
    ob[2 * P] = acc2;
}

extern "C" void kernel_launch(void* const* d_in, const int* in_sizes, int n_in,
                              void* d_out, int out_size, void* d_ws, size_t ws_size,
                              hipStream_t stream) {
    const float* inp  = (const float*)d_in[0];
    const float* vert = (const float*)d_in[1];
    const float* horz = (const float*)d_in[2];
    const float* offX = (const float*)d_in[3];
    const float* offY = (const float*)d_in[4];
    const float* mask = (const float*)d_in[5];
    float* out = (float*)d_out;

    // grid: B * (HO/4) * (WO/64) = 4 * 64 * 4 = 1024 blocks
    dim3 block(256);
    dim3 grid(B * (HO / 4) * (WO / 64));
    dsepconv_kernel<<<grid, block, 0, stream>>>(inp, vert, horz, offX, offY, mask, out);
}

// Round 10
// 26.545 us; speedup vs baseline: 1.0870x; 1.0870x over previous
//
#include <hip/hip_runtime.h>
#include <hip/hip_fp16.h>

// Problem constants (match reference)
constexpr int B  = 4;
constexpr int C  = 3;
constexpr int F  = 5;
constexpr int HO = 256;
constexpr int WO = 256;
constexpr int HI = HO + F - 1; // 260
constexpr int WI = WO + F - 1; // 260
constexpr int P  = HO * WO;    // 65536 pixels per (b, map)
constexpr int FF = F * F;      // 25
constexpr int PI = HI * WI;    // 67600 input pixels per (b, c)

// Block = 512 threads = 8 waves; patch (y0..y0+3, x0..x0+63).
// Wave w: y-row y0+(w>>1), tap-half (w&1): k in [0,12) or [12,25).
// -> 8192 waves total, 32 waves/CU resident (TLP of R8) with the 64x4
// patch's staging amortization (5.25 staged entries/pixel, R9).
// Tile: rows [y0-7, y0+13] (21) x cols [x0-7, x0+72] (80), fp16 uint2.
constexpr int TROWS = 21;
constexpr int TCOLS = 80;
constexpr int TSTRIDE = 81;            // 8B units
constexpr int TN = TROWS * TCOLS;      // 1680 entries
constexpr int AMAX = (TROWS - 2) * TSTRIDE + (TCOLS - 2);

__device__ __forceinline__ uint2 pack3(float a, float b, float c) {
    __half2 ab = __floats2half2_rn(a, b);
    __half2 cz = __floats2half2_rn(c, 0.0f);
    uint2 r;
    r.x = *reinterpret_cast<const unsigned int*>(&ab);
    r.y = *reinterpret_cast<const unsigned int*>(&cz);
    return r;
}

__device__ __forceinline__ void fmacc(uint2 v, float w,
                                      float& a0, float& a1, float& a2) {
    __half2 ab = *reinterpret_cast<const __half2*>(&v.x);
    __half2 cz = *reinterpret_cast<const __half2*>(&v.y);
    // (float)half * f32 + f32 acc -> v_fma_mix_f32
    a0 += __half2float(__low2half(ab))  * w;
    a1 += __half2float(__high2half(ab)) * w;
    a2 += __half2float(__low2half(cz))  * w;
}

__global__ __launch_bounds__(512, 8) void dsepconv_kernel(
    const float* __restrict__ inp,   // (B, C, HI, WI)
    const float* __restrict__ vert,  // (B, F, HO, WO)
    const float* __restrict__ horz,  // (B, F, HO, WO)
    const float* __restrict__ offX,  // -> py (vertical), per reference
    const float* __restrict__ offY,  // -> px (horizontal), per reference
    const float* __restrict__ mask,  // (B, F*F, HO, WO)
    float* __restrict__ out)         // (B, C, HO, WO)
{
    __shared__ uint2 tileq[TROWS * TSTRIDE];  // 13,608 B
    __shared__ float red[4][3][64];           // 3,072 B: half-1 partials

    const int tid  = threadIdx.x;
    const int lane = tid & 63;
    const int wave = tid >> 6;                 // 0..7
    const int wrow = wave >> 1;                // 0..3: y-row in patch
    const int half = wave & 1;                 // 0..1: tap half

    // Grid: bx = b*256 + yblk*4 + xblk
    const int bx   = blockIdx.x;
    const int x0   = (bx & 3) * 64;
    const int y0   = ((bx >> 2) & 63) * 4;
    const int b    = bx >> 8;

    const float* in0 = inp + (size_t)b * C * PI;
    const float* in1 = in0 + PI;
    const float* in2 = in1 + PI;

    // ---- Stage tile: rows [y0-7, y0+13], cols [x0-7, x0+72] ----
    const int ry0 = y0 - 7;
    const int cx0 = x0 - 7;
#pragma unroll 1
    for (int e = tid; e < TN; e += 512) {
        int trow = e / TCOLS;
        int tcol = e - trow * TCOLS;
        int gy = min(max(ry0 + trow, 0), HI - 1);
        int gx = min(max(cx0 + tcol, 0), WI - 1);
        int g = gy * WI + gx;
        tileq[trow * TSTRIDE + tcol] = pack3(in0[g], in1[g], in2[g]);
    }
    __syncthreads();

    const int x   = x0 + lane;
    const int y   = y0 + wrow;
    const int pix = y * WO + x;

    const float* offXb = offX + (size_t)b * FF * P + pix;
    const float* offYb = offY + (size_t)b * FF * P + pix;
    const float* maskb = mask + (size_t)b * FF * P + pix;
    const float* vb    = vert + (size_t)b * F * P + pix;
    const float* hb    = horz + (size_t)b * F * P + pix;

    float acc0 = 0.f, acc1 = 0.f, acc2 = 0.f;

    const int k0 = half ? 12 : 0;
    const int k1 = half ? 25 : 12;

#pragma unroll 1
    for (int k = k0; k < k1; ++k) {
        const int i = k / F;          // magic-mul, cheap
        const int j = k - i * F;

        float oy = offYb[k * P];
        float ox = offXb[k * P];
        float m  = maskb[k * P];
        float h  = hb[j * P];
        float v  = vb[i * P];         // L1-hot (few distinct addrs)

        // px = clip(offY + x + j - half + 1, 0, WI-1); half = 2
        float px = fminf(fmaxf(oy + (float)(x + j - 1), 0.0f), (float)(WI - 1));
        float py = fminf(fmaxf(ox + (float)(y + i - 1), 0.0f), (float)(HI - 1));

        float lf = floorf(px);
        float tf = floorf(py);
        int l = (int)lf;
        int t = (int)tf;
        float wx = 1.0f - (px - lf);
        float wy = 1.0f - (py - tf);

        // Bilinear identity: clamped edge => r/bottom weights exactly 0,
        // so always read l+1 / t+1 (tile has the +1 margin).
        float w   = v * h * m;
        float wyw = wy * w;
        float wbw = w - wyw;
        float wtl = wx * wyw;
        float wtr = wyw - wtl;
        float wbl = wx * wbw;
        float wbr = wbw - wbl;

        int lt = t - ry0;
        int ll = l - cx0;
        bool ok = ((unsigned)lt <= TROWS - 2) & ((unsigned)ll <= TCOLS - 2);

        int a = min(max(lt * TSTRIDE + ll, 0), AMAX); // safe for !ok lanes

        uint2 g_tl = tileq[a];
        uint2 g_tr = tileq[a + 1];
        uint2 g_bl = tileq[a + TSTRIDE];
        uint2 g_br = tileq[a + TSTRIDE + 1];

        // rare fallback: offset beyond tile margin (~1e-9/sample)
        if (__any(!ok)) {
            if (!ok) {
                int r  = min(l + 1, WI - 1);
                int bt = min(t + 1, HI - 1);
                int o_tl = t * WI + l,  o_tr = t * WI + r;
                int o_bl = bt * WI + l, o_br = bt * WI + r;
                g_tl = pack3(in0[o_tl], in1[o_tl], in2[o_tl]);
                g_tr = pack3(in0[o_tr], in1[o_tr], in2[o_tr]);
                g_bl = pack3(in0[o_bl], in1[o_bl], in2[o_bl]);
                g_br = pack3(in0[o_br], in1[o_br], in2[o_br]);
            }
        }

        fmacc(g_tl, wtl, acc0, acc1, acc2);
        fmacc(g_tr, wtr, acc0, acc1, acc2);
        fmacc(g_bl, wbl, acc0, acc1, acc2);
        fmacc(g_br, wbr, acc0, acc1, acc2);
    }

    // ---- Combine the two tap-halves per row ----
    if (half) {
        red[wrow][0][lane] = acc0;
        red[wrow][1][lane] = acc1;
        red[wrow][2][lane] = acc2;
    }
    __syncthreads();

    if (!half) {
        float* ob = out + (size_t)b * C * P + pix;
        ob[0]     = acc0 + red[wrow][0][lane];
        ob[P]     = acc1 + red[wrow][1][lane];
        ob[2 * P] = acc2 + red[wrow][2][lane];
    }
}

extern "C" void kernel_launch(void* const* d_in, const int* in_sizes, int n_in,
                              void* d_out, int out_size, void* d_ws, size_t ws_size,
                              hipStream_t stream) {
    const float* inp  = (const float*)d_in[0];
    const float* vert = (const float*)d_in[1];
    const float* horz = (const float*)d_in[2];
    const float* offX = (const float*)d_in[3];
    const float* offY = (const float*)d_in[4];
    const float* mask = (const float*)d_in[5];
    float* out = (float*)d_out;

    // grid: B * (HO/4) * (WO/64) = 4 * 64 * 4 = 1024 blocks, 512 thr each
    dim3 block(512);
    dim3 grid(B * (HO / 4) * (WO / 64));
    dsepconv_kernel<<<grid, block, 0, stream>>>(inp, vert, horz, offX, offY, mask, out);
}

// Round 11
// 26.154 us; speedup vs baseline: 1.1033x; 1.0150x over previous
//
#include <hip/hip_runtime.h>
#include <hip/hip_fp16.h>

// Problem constants (match reference)
constexpr int B  = 4;
constexpr int C  = 3;
constexpr int F  = 5;
constexpr int HO = 256;
constexpr int WO = 256;
constexpr int HI = HO + F - 1; // 260
constexpr int WI = WO + F - 1; // 260
constexpr int P  = HO * WO;    // 65536 pixels per (b, map)
constexpr int FF = F * F;      // 25
constexpr int PI = HI * WI;    // 67600 input pixels per (b, c)

// Block = 512 threads = 8 waves; patch (y0..y0+3, x0..x0+63).
// Wave w: y-row y0+(w>>1), tap-half (w&1): k in [0,12) or [12,25).
// 2-deep software pipeline on streaming loads: tap k+1's loads issue while
// tap k computes; first tap prefetched BEFORE the staging barrier (its
// vmcnt(0) drain completes them under the staging latency).
// Tile: rows [y0-7, y0+13] (21) x cols [x0-7, x0+72] (80), fp16 uint2.
constexpr int TROWS = 21;
constexpr int TCOLS = 80;
constexpr int TSTRIDE = 81;            // 8B units
constexpr int TN = TROWS * TCOLS;      // 1680 entries
constexpr int AMAX = (TROWS - 2) * TSTRIDE + (TCOLS - 2);

__device__ __forceinline__ uint2 pack3(float a, float b, float c) {
    __half2 ab = __floats2half2_rn(a, b);
    __half2 cz = __floats2half2_rn(c, 0.0f);
    uint2 r;
    r.x = *reinterpret_cast<const unsigned int*>(&ab);
    r.y = *reinterpret_cast<const unsigned int*>(&cz);
    return r;
}

__device__ __forceinline__ void fmacc(uint2 v, float w,
                                      float& a0, float& a1, float& a2) {
    __half2 ab = *reinterpret_cast<const __half2*>(&v.x);
    __half2 cz = *reinterpret_cast<const __half2*>(&v.y);
    // (float)half * f32 + f32 acc -> v_fma_mix_f32
    a0 += __half2float(__low2half(ab))  * w;
    a1 += __half2float(__high2half(ab)) * w;
    a2 += __half2float(__low2half(cz))  * w;
}

__global__ __launch_bounds__(512, 8) void dsepconv_kernel(
    const float* __restrict__ inp,   // (B, C, HI, WI)
    const float* __restrict__ vert,  // (B, F, HO, WO)
    const float* __restrict__ horz,  // (B, F, HO, WO)
    const float* __restrict__ offX,  // -> py (vertical), per reference
    const float* __restrict__ offY,  // -> px (horizontal), per reference
    const float* __restrict__ mask,  // (B, F*F, HO, WO)
    float* __restrict__ out)         // (B, C, HO, WO)
{
    __shared__ uint2 tileq[TROWS * TSTRIDE];  // 13,608 B
    __shared__ float red[4][3][64];           // 3,072 B: half-1 partials

    const int tid  = threadIdx.x;
    const int lane = tid & 63;
    const int wave = tid >> 6;                 // 0..7
    const int wrow = wave >> 1;                // 0..3: y-row in patch
    const int half = wave & 1;                 // 0..1: tap half

    // Grid: bx = b*256 + yblk*4 + xblk
    const int bx   = blockIdx.x;
    const int x0   = (bx & 3) * 64;
    const int y0   = ((bx >> 2) & 63) * 4;
    const int b    = bx >> 8;

    const float* in0 = inp + (size_t)b * C * PI;
    const float* in1 = in0 + PI;
    const float* in2 = in1 + PI;

    const int x   = x0 + lane;
    const int y   = y0 + wrow;
    const int pix = y * WO + x;

    const float* offXb = offX + (size_t)b * FF * P + pix;
    const float* offYb = offY + (size_t)b * FF * P + pix;
    const float* maskb = mask + (size_t)b * FF * P + pix;
    const float* vb    = vert + (size_t)b * F * P + pix;
    const float* hb    = horz + (size_t)b * F * P + pix;

    const int k0 = half ? 12 : 0;
    const int k1 = half ? 25 : 12;

    // ---- Prefetch first tap's streaming values (completes under barrier) ----
    float oy, ox, m, h, v;
    {
        const int i = k0 / F, j = k0 - (k0 / F) * F;
        oy = offYb[k0 * P];
        ox = offXb[k0 * P];
        m  = maskb[k0 * P];
        h  = hb[j * P];
        v  = vb[i * P];
    }

    // ---- Stage tile: rows [y0-7, y0+13], cols [x0-7, x0+72] ----
    const int ry0 = y0 - 7;
    const int cx0 = x0 - 7;
#pragma unroll 1
    for (int e = tid; e < TN; e += 512) {
        int trow = e / TCOLS;
        int tcol = e - trow * TCOLS;
        int gy = min(max(ry0 + trow, 0), HI - 1);
        int gx = min(max(cx0 + tcol, 0), WI - 1);
        int g = gy * WI + gx;
        tileq[trow * TSTRIDE + tcol] = pack3(in0[g], in1[g], in2[g]);
    }
    __syncthreads();

    float acc0 = 0.f, acc1 = 0.f, acc2 = 0.f;

#pragma unroll 1
    for (int k = k0; k < k1; ++k) {
        const int i = k / F;
        const int j = k - i * F;

        // ---- issue NEXT tap's streaming loads (overlap with this compute) ----
        const int kn = (k + 1 < k1) ? k + 1 : k;   // last iter: harmless reload
        const int in_ = kn / F;
        const int jn  = kn - in_ * F;
        float oy_n = offYb[kn * P];
        float ox_n = offXb[kn * P];
        float m_n  = maskb[kn * P];
        float h_n  = hb[jn * P];
        float v_n  = vb[in_ * P];

        // ---- compute current tap from registers ----
        // px = clip(offY + x + j - half + 1, 0, WI-1); half = 2
        float px = fminf(fmaxf(oy + (float)(x + j - 1), 0.0f), (float)(WI - 1));
        float py = fminf(fmaxf(ox + (float)(y + i - 1), 0.0f), (float)(HI - 1));

        float lf = floorf(px);
        float tf = floorf(py);
        int l = (int)lf;
        int t = (int)tf;
        float wx = 1.0f - (px - lf);
        float wy = 1.0f - (py - tf);

        // Bilinear identity: clamped edge => r/bottom weights exactly 0,
        // so always read l+1 / t+1 (tile has the +1 margin).
        float w   = v * h * m;
        float wyw = wy * w;
        float wbw = w - wyw;
        float wtl = wx * wyw;
        float wtr = wyw - wtl;
        float wbl = wx * wbw;
        float wbr = wbw - wbl;

        int lt = t - ry0;
        int ll = l - cx0;
        bool ok = ((unsigned)lt <= TROWS - 2) & ((unsigned)ll <= TCOLS - 2);

        int a = min(max(lt * TSTRIDE + ll, 0), AMAX); // safe for !ok lanes

        uint2 g_tl = tileq[a];
        uint2 g_tr = tileq[a + 1];
        uint2 g_bl = tileq[a + TSTRIDE];
        uint2 g_br = tileq[a + TSTRIDE + 1];

        // rare fallback: offset beyond tile margin (~1e-9/sample)
        if (__any(!ok)) {
            if (!ok) {
                int r  = min(l + 1, WI - 1);
                int bt = min(t + 1, HI - 1);
                int o_tl = t * WI + l,  o_tr = t * WI + r;
                int o_bl = bt * WI + l, o_br = bt * WI + r;
                g_tl = pack3(in0[o_tl], in1[o_tl], in2[o_tl]);
                g_tr = pack3(in0[o_tr], in1[o_tr], in2[o_tr]);
                g_bl = pack3(in0[o_bl], in1[o_bl], in2[o_bl]);
                g_br = pack3(in0[o_br], in1[o_br], in2[o_br]);
            }
        }

        fmacc(g_tl, wtl, acc0, acc1, acc2);
        fmacc(g_tr, wtr, acc0, acc1, acc2);
        fmacc(g_bl, wbl, acc0, acc1, acc2);
        fmacc(g_br, wbr, acc0, acc1, acc2);

        // ---- rotate pipeline ----
        oy = oy_n; ox = ox_n; m = m_n; h = h_n; v = v_n;
    }

    // ---- Combine the two tap-halves per row ----
    if (half) {
        red[wrow][0][lane] = acc0;
        red[wrow][1][lane] = acc1;
        red[wrow][2][lane] = acc2;
    }
    __syncthreads();

    if (!half) {
        float* ob = out + (size_t)b * C * P + pix;
        ob[0]     = acc0 + red[wrow][0][lane];
        ob[P]     = acc1 + red[wrow][1][lane];
        ob[2 * P] = acc2 + red[wrow][2][lane];
    }
}

extern "C" void kernel_launch(void* const* d_in, const int* in_sizes, int n_in,
                              void* d_out, int out_size, void* d_ws, size_t ws_size,
                              hipStream_t stream) {
    const float* inp  = (const float*)d_in[0];
    const float* vert = (const float*)d_in[1];
    const float* horz = (const float*)d_in[2];
    const float* offX = (const float*)d_in[3];
    const float* offY = (const float*)d_in[4];
    const float* mask = (const float*)d_in[5];
    float* out = (float*)d_out;

    // grid: B * (HO/4) * (WO/64) = 4 * 64 * 4 = 1024 blocks, 512 thr each
    dim3 block(512);
    dim3 grid(B * (HO / 4) * (WO / 64));
    dsepconv_kernel<<<grid, block, 0, stream>>>(inp, vert, horz, offX, offY, mask, out);
}